// Round 1
// baseline (640.937 us; speedup 1.0000x reference)
//
#include <hip/hip_runtime.h>
#include <hip/hip_bf16.h>

#define NATOM 50000
#define MNBR  32
#define NEDGE (NATOM * MNBR)   // 1,600,000 (divisible by 16)
#define ATOMF 128
#define NBRF  64
#define SHDIM 9
#define NREP_MAX 8             // scatter-accumulator replicas (contention /8)

typedef float  f32x4  __attribute__((ext_vector_type(4)));
typedef __bf16 bf16x8 __attribute__((ext_vector_type(8)));

// Native-op softplus: max(x,0) + ln2 * log2(1 + exp2(-|x|*log2e)).
// v_exp_f32/v_log_f32 are ~2-ULP; error invisible under bf16 matmul noise.
__device__ __forceinline__ float softplus_f(float x) {
    float e = __builtin_amdgcn_exp2f(-fabsf(x) * 1.44269504089f);
    float l = __builtin_amdgcn_logf(1.0f + e);   // log2
    return fmaxf(x, 0.0f) + 0.69314718056f * l;
}

__device__ __forceinline__ bf16x8 to_bf16x8(float4 lo, float4 hi) {
    bf16x8 r;
    r[0] = (__bf16)lo.x; r[1] = (__bf16)lo.y; r[2] = (__bf16)lo.z; r[3] = (__bf16)lo.w;
    r[4] = (__bf16)hi.x; r[5] = (__bf16)hi.y; r[6] = (__bf16)hi.z; r[7] = (__bf16)hi.w;
    return r;
}

// Edge kernel: per edge e, scalar_e = softplus(nbr_fea_e @ w1 + b1) . w2[:,0]
// (b2[0] deferred to the rescale: S_true = S + C*b2).
// Scatter: SC is NREP replicas of an interleaved [S|C] pair array:
//   SC[rep][2j] += scalar_e, SC[rep][2j+1] += 1, rep = blockIdx & rep_mask.
// Interleaving puts both atomics of an edge in the same cache line; replication
// cuts same-word contention 8x and keeps atomics roughly XCD-local under
// round-robin block dispatch. Atomics are issued wave-wide (16 active lanes,
// 2 instructions/tile) instead of 8 instructions from 4 lanes.
__global__ __launch_bounds__(256, 4) void edge_kernel(
    const float* __restrict__ nbr_fea, const int* __restrict__ nbr_idx,
    const float* __restrict__ w1, const float* __restrict__ b1,
    const float* __restrict__ w2,
    float* __restrict__ SC, int rep_mask)
{
    const int lane = threadIdx.x & 63;
    const int m    = lane & 15;    // A-row index (edge) / D-col index (feature)
    const int quad = lane >> 4;    // k-block / D-row-block index
    const int wave_id = (int)((blockIdx.x * blockDim.x + threadIdx.x) >> 6);
    const int nwaves  = (int)((gridDim.x * blockDim.x) >> 6);

    float* mySC = SC + (size_t)(blockIdx.x & (unsigned)rep_mask) * (2 * NATOM);

    // B fragments: B[k][n] = w1[k][n]; lane holds k = c*32 + quad*8 + j, n = nb*16 + m
    bf16x8 bfrag[2][4];
#pragma unroll
    for (int c = 0; c < 2; ++c)
#pragma unroll
        for (int nb = 0; nb < 4; ++nb)
#pragma unroll
            for (int j = 0; j < 8; ++j)
                bfrag[c][nb][j] = (__bf16)w1[(c * 32 + quad * 8 + j) * NBRF + nb * 16 + m];

    float b1v[4], w2v[4];
#pragma unroll
    for (int nb = 0; nb < 4; ++nb) {
        b1v[nb] = b1[nb * 16 + m];
        w2v[nb] = w2[(nb * 16 + m) * SHDIM + 0];  // w2 is (64,9) row-major; col 0
    }

    const int ntiles = NEDGE / 16;
    for (int t = wave_id; t < ntiles; t += nwaves) {
        const int e0 = t * 16;

        // idx load hoisted ahead of the MFMA chain: lanes 0..15 own edges e0..e0+15
        int jj = 0;
        if (lane < 16) {
            jj = nbr_idx[e0 + lane];
            jj = (jj < 0) ? 0 : (jj >= NATOM ? NATOM - 1 : jj);  // never fault
        }

        // A fragments: A[m][k], k = c*32 + quad*8 + j  -> two float4 loads per chunk
        bf16x8 afrag[2];
#pragma unroll
        for (int c = 0; c < 2; ++c) {
            const float* base = &nbr_fea[(size_t)(e0 + m) * NBRF + c * 32 + quad * 8];
            const float4 f0 = *(const float4*)(base);
            const float4 f1 = *(const float4*)(base + 4);
            afrag[c] = to_bf16x8(f0, f1);
        }

        f32x4 acc[4] = { {0.f,0.f,0.f,0.f}, {0.f,0.f,0.f,0.f},
                         {0.f,0.f,0.f,0.f}, {0.f,0.f,0.f,0.f} };
#pragma unroll
        for (int c = 0; c < 2; ++c)
#pragma unroll
            for (int nb = 0; nb < 4; ++nb)
                acc[nb] = __builtin_amdgcn_mfma_f32_16x16x32_bf16(
                    afrag[c], bfrag[c][nb], acc[nb], 0, 0, 0);

        // D layout: col(feature) = nb*16 + m, row(edge-local) = quad*4 + reg
        float part[4] = {0.f, 0.f, 0.f, 0.f};
#pragma unroll
        for (int nb = 0; nb < 4; ++nb)
#pragma unroll
            for (int r = 0; r < 4; ++r)
                part[r] += softplus_f(acc[nb][r] + b1v[nb]) * w2v[nb];

        // butterfly over the 16 lanes of the quad-group (feature dimension);
        // afterwards every lane in the group holds the full sum
#pragma unroll
        for (int off = 1; off < 16; off <<= 1)
#pragma unroll
            for (int r = 0; r < 4; ++r)
                part[r] += __shfl_xor(part[r], off, 64);

        // redistribute: lane l (<16) takes edge e0+l = (quad'=l>>2, r'=l&3)
        // from lane quad'*16 (any lane of that group works post-butterfly)
        const int src = ((lane & 15) >> 2) << 4;
        const float t0 = __shfl(part[0], src, 64);
        const float t1 = __shfl(part[1], src, 64);
        const float t2 = __shfl(part[2], src, 64);
        const float t3 = __shfl(part[3], src, 64);
        const int rr = lane & 3;
        const float val = (rr == 0) ? t0 : (rr == 1) ? t1 : (rr == 2) ? t2 : t3;

        if (lane < 16) {
            atomicAdd(&mySC[2 * jj],     val);   // adjacent words: same L2 line
            atomicAdd(&mySC[2 * jj + 1], 1.0f);
        }
    }
}

// Atom kernel: out[j][f] = (atom_fea[j] @ tp_w)[f] * (S[j]+C[j]*b2)/max(C[j],1)/sqrt(128)
// S,C reduced over the NREP interleaved replicas. bf16 MFMA GEMM: one block
// (4 waves) per 16-atom tile, wave w owns features [w*32, w*32+32).
__global__ __launch_bounds__(256) void atom_kernel(
    const float* __restrict__ atom_fea, const float* __restrict__ tp_w,
    const float* __restrict__ SC, const float* __restrict__ b2,
    float* __restrict__ out, int nrep)
{
    const int lane = threadIdx.x & 63;
    const int wave = threadIdx.x >> 6;   // feature half-block: nb_global = wave*2 + nb
    const int m    = lane & 15;
    const int quad = lane >> 4;
    const float b2_0 = b2[0];

    // B fragments: B[k][n] = tp_w[k][n]; k = c*32 + quad*8 + j, n = (wave*2+nb)*16 + m
    bf16x8 bfrag[4][2];
#pragma unroll
    for (int c = 0; c < 4; ++c)
#pragma unroll
        for (int nb = 0; nb < 2; ++nb)
#pragma unroll
            for (int j = 0; j < 8; ++j)
                bfrag[c][nb][j] =
                    (__bf16)tp_w[(c * 32 + quad * 8 + j) * ATOMF + (wave * 2 + nb) * 16 + m];

    const int ntiles = NATOM / 16;  // 3125
    for (int t = blockIdx.x; t < ntiles; t += gridDim.x) {
        const int j0 = t * 16;

        // A fragments: A[m][k] = atom_fea[j0+m][k]
        bf16x8 afrag[4];
#pragma unroll
        for (int c = 0; c < 4; ++c) {
            const float* base = &atom_fea[(size_t)(j0 + m) * ATOMF + c * 32 + quad * 8];
            const float4 f0 = *(const float4*)(base);
            const float4 f1 = *(const float4*)(base + 4);
            afrag[c] = to_bf16x8(f0, f1);
        }

        f32x4 acc[2] = { {0.f,0.f,0.f,0.f}, {0.f,0.f,0.f,0.f} };
#pragma unroll
        for (int c = 0; c < 4; ++c)
#pragma unroll
            for (int nb = 0; nb < 2; ++nb)
                acc[nb] = __builtin_amdgcn_mfma_f32_16x16x32_bf16(
                    afrag[c], bfrag[c][nb], acc[nb], 0, 0, 0);

        // scales for rows quad*4 + r: compute once per quad-group (m==0), broadcast
        float sc[4] = {0.f, 0.f, 0.f, 0.f};
        if (m == 0) {
#pragma unroll
            for (int r = 0; r < 4; ++r) {
                const int j = j0 + quad * 4 + r;
                float s = 0.f, c = 0.f;
                for (int p = 0; p < nrep; ++p) {
                    s += SC[(size_t)p * (2 * NATOM) + 2 * j];
                    c += SC[(size_t)p * (2 * NATOM) + 2 * j + 1];
                }
                // S_true = s + c*b2; out scale = S_true/max(c,1)/sqrt(128)
                sc[r] = (s + c * b2_0) / fmaxf(c, 1.0f) * 0.08838834764831843f;
            }
        }
#pragma unroll
        for (int r = 0; r < 4; ++r)
            sc[r] = __shfl(sc[r], quad << 4, 64);

#pragma unroll
        for (int nb = 0; nb < 2; ++nb)
#pragma unroll
            for (int r = 0; r < 4; ++r)
                out[(size_t)(j0 + quad * 4 + r) * ATOMF + (wave * 2 + nb) * 16 + m] =
                    acc[nb][r] * sc[r];
    }
}

extern "C" void kernel_launch(void* const* d_in, const int* in_sizes, int n_in,
                              void* d_out, int out_size, void* d_ws, size_t ws_size,
                              hipStream_t stream) {
    const float* atom_fea = (const float*)d_in[0];
    const float* nbr_fea  = (const float*)d_in[1];
    const int*   nbr_idx  = (const int*)d_in[2];    // harness delivers integer inputs as int32
    const float* w1       = (const float*)d_in[3];
    const float* b1       = (const float*)d_in[4];
    const float* w2       = (const float*)d_in[5];
    const float* b2       = (const float*)d_in[6];
    const float* tp_w     = (const float*)d_in[7];
    float* out = (float*)d_out;

    float* SC = (float*)d_ws;       // nrep x [50000 x (scalar_sum, count) interleaved]

    int nrep = (ws_size >= (size_t)NREP_MAX * 2 * NATOM * sizeof(float)) ? NREP_MAX : 1;

    hipMemsetAsync(d_ws, 0, (size_t)nrep * 2 * NATOM * sizeof(float), stream);

    edge_kernel<<<2048, 256, 0, stream>>>(nbr_fea, nbr_idx, w1, b1, w2, SC, nrep - 1);
    atom_kernel<<<1024, 256, 0, stream>>>(atom_fea, tp_w, SC, b2, out, nrep);
}

// Round 2
// 622.095 us; speedup vs baseline: 1.0303x; 1.0303x over previous
//
#include <hip/hip_runtime.h>
#include <hip/hip_bf16.h>

#define NATOM 50000
#define MNBR  32
#define NEDGE (NATOM * MNBR)   // 1,600,000 (divisible by 16)
#define ATOMF 128
#define NBRF  64
#define SHDIM 9
#define NREP_MAX 8             // scatter-accumulator replicas (contention /8)

typedef float  f32x4  __attribute__((ext_vector_type(4)));
typedef __bf16 bf16x8 __attribute__((ext_vector_type(8)));

// Native-op softplus: max(x,0) + ln2 * log2(1 + exp2(-|x|*log2e)).
// v_exp_f32/v_log_f32 are ~2-ULP; error invisible under bf16 matmul noise.
__device__ __forceinline__ float softplus_f(float x) {
    float e = __builtin_amdgcn_exp2f(-fabsf(x) * 1.44269504089f);
    float l = __builtin_amdgcn_logf(1.0f + e);   // log2
    return fmaxf(x, 0.0f) + 0.69314718056f * l;
}

__device__ __forceinline__ bf16x8 to_bf16x8(float4 lo, float4 hi) {
    bf16x8 r;
    r[0] = (__bf16)lo.x; r[1] = (__bf16)lo.y; r[2] = (__bf16)lo.z; r[3] = (__bf16)lo.w;
    r[4] = (__bf16)hi.x; r[5] = (__bf16)hi.y; r[6] = (__bf16)hi.z; r[7] = (__bf16)hi.w;
    return r;
}

// Edge kernel: per edge e, scalar_e = softplus(nbr_fea_e @ w1 + b1) . w2[:,0]
// (b2[0] deferred to the rescale: S_true = S + C*b2).
// One-deep software pipeline: the next tile's 4 float4 A-loads + idx load are
// issued before the current tile's MFMA/softplus/shfl tail, so HBM latency
// hides under ~400 cycles of compute (cross-tile MLP, not just TLP).
// Scatter: SC is NREP replicas of an interleaved [S|C] pair array;
// rep = blockIdx & rep_mask (XCD-local under round-robin dispatch).
__global__ __launch_bounds__(256, 4) void edge_kernel(
    const float* __restrict__ nbr_fea, const int* __restrict__ nbr_idx,
    const float* __restrict__ w1, const float* __restrict__ b1,
    const float* __restrict__ w2,
    float* __restrict__ SC, int rep_mask)
{
    const int lane = threadIdx.x & 63;
    const int m    = lane & 15;    // A-row index (edge) / D-col index (feature)
    const int quad = lane >> 4;    // k-block / D-row-block index
    const int wave_id = (int)((blockIdx.x * blockDim.x + threadIdx.x) >> 6);
    const int nwaves  = (int)((gridDim.x * blockDim.x) >> 6);

    float* mySC = SC + (size_t)(blockIdx.x & (unsigned)rep_mask) * (2 * NATOM);

    // B fragments: B[k][n] = w1[k][n]; lane holds k = c*32 + quad*8 + j, n = nb*16 + m
    bf16x8 bfrag[2][4];
#pragma unroll
    for (int c = 0; c < 2; ++c)
#pragma unroll
        for (int nb = 0; nb < 4; ++nb)
#pragma unroll
            for (int j = 0; j < 8; ++j)
                bfrag[c][nb][j] = (__bf16)w1[(c * 32 + quad * 8 + j) * NBRF + nb * 16 + m];

    float b1v[4], w2v[4];
#pragma unroll
    for (int nb = 0; nb < 4; ++nb) {
        b1v[nb] = b1[nb * 16 + m];
        w2v[nb] = w2[(nb * 16 + m) * SHDIM + 0];  // w2 is (64,9) row-major; col 0
    }

    const int ntiles = NEDGE / 16;
    int t = wave_id;
    if (t >= ntiles) return;

    // prologue: prefetch tile t  (offsets within row: c*32 + quad*8 (+4))
    float4 pf0, pf1, pf2, pf3;
    int pjj;
    {
        const float* base = &nbr_fea[(size_t)(t * 16 + m) * NBRF + quad * 8];
        pf0 = *(const float4*)(base);
        pf1 = *(const float4*)(base + 4);
        pf2 = *(const float4*)(base + 32);
        pf3 = *(const float4*)(base + 36);
        pjj = nbr_idx[t * 16 + (lane & 15)];   // all lanes: avoids exec-mask dance
    }

    for (;;) {
        const int e0 = t * 16;
        const int tn = t + nwaves;
        const bool more = (tn < ntiles);

        // consume prefetch into fragments before overwriting
        const bf16x8 af0 = to_bf16x8(pf0, pf1);
        const bf16x8 af1 = to_bf16x8(pf2, pf3);
        int jj = pjj;
        jj = (jj < 0) ? 0 : (jj >= NATOM ? NATOM - 1 : jj);  // never fault

        // issue next tile's loads now; waitcnt lands at next iteration's cvt
        if (more) {
            const float* base = &nbr_fea[(size_t)(tn * 16 + m) * NBRF + quad * 8];
            pf0 = *(const float4*)(base);
            pf1 = *(const float4*)(base + 4);
            pf2 = *(const float4*)(base + 32);
            pf3 = *(const float4*)(base + 36);
            pjj = nbr_idx[tn * 16 + (lane & 15)];
        }

        f32x4 acc[4] = { {0.f,0.f,0.f,0.f}, {0.f,0.f,0.f,0.f},
                         {0.f,0.f,0.f,0.f}, {0.f,0.f,0.f,0.f} };
#pragma unroll
        for (int nb = 0; nb < 4; ++nb) {
            acc[nb] = __builtin_amdgcn_mfma_f32_16x16x32_bf16(af0, bfrag[0][nb], acc[nb], 0, 0, 0);
            acc[nb] = __builtin_amdgcn_mfma_f32_16x16x32_bf16(af1, bfrag[1][nb], acc[nb], 0, 0, 0);
        }

        // D layout: col(feature) = nb*16 + m, row(edge-local) = quad*4 + reg
        float part[4] = {0.f, 0.f, 0.f, 0.f};
#pragma unroll
        for (int nb = 0; nb < 4; ++nb)
#pragma unroll
            for (int r = 0; r < 4; ++r)
                part[r] += softplus_f(acc[nb][r] + b1v[nb]) * w2v[nb];

        // butterfly over the 16 lanes of the quad-group (feature dimension)
#pragma unroll
        for (int off = 1; off < 16; off <<= 1)
#pragma unroll
            for (int r = 0; r < 4; ++r)
                part[r] += __shfl_xor(part[r], off, 64);

        // redistribute: lane l (<16) takes edge e0+l from lane (l>>2)*16
        const int src = ((lane & 15) >> 2) << 4;
        const float t0 = __shfl(part[0], src, 64);
        const float t1 = __shfl(part[1], src, 64);
        const float t2 = __shfl(part[2], src, 64);
        const float t3 = __shfl(part[3], src, 64);
        const int rr = lane & 3;
        const float val = (rr == 0) ? t0 : (rr == 1) ? t1 : (rr == 2) ? t2 : t3;

        if (lane < 16) {
            atomicAdd(&mySC[2 * jj],     val);   // adjacent words: same L2 line
            atomicAdd(&mySC[2 * jj + 1], 1.0f);
        }

        if (!more) break;
        t = tn;
    }
}

// Atom kernel: out[j][f] = (atom_fea[j] @ tp_w)[f] * (S[j]+C[j]*b2)/max(C[j],1)/sqrt(128)
// S,C reduced over the NREP interleaved replicas with a parallel 16-lane
// pattern (1 load/lane + 8-lane butterfly) instead of 64 serial loads on m==0.
__global__ __launch_bounds__(256) void atom_kernel(
    const float* __restrict__ atom_fea, const float* __restrict__ tp_w,
    const float* __restrict__ SC, const float* __restrict__ b2,
    float* __restrict__ out, int nrep)
{
    const int lane = threadIdx.x & 63;
    const int wave = threadIdx.x >> 6;   // feature half-block: nb_global = wave*2 + nb
    const int m    = lane & 15;
    const int quad = lane >> 4;
    const float b2_0 = b2[0];

    // B fragments: B[k][n] = tp_w[k][n]; k = c*32 + quad*8 + j, n = (wave*2+nb)*16 + m
    bf16x8 bfrag[4][2];
#pragma unroll
    for (int c = 0; c < 4; ++c)
#pragma unroll
        for (int nb = 0; nb < 2; ++nb)
#pragma unroll
            for (int j = 0; j < 8; ++j)
                bfrag[c][nb][j] =
                    (__bf16)tp_w[(c * 32 + quad * 8 + j) * ATOMF + (wave * 2 + nb) * 16 + m];

    const int p     = m & 7;      // replica this lane reduces
    const int which = m >> 3;     // 0 = scalar-sum word, 1 = count word

    const int ntiles = NATOM / 16;  // 3125
    for (int t = blockIdx.x; t < ntiles; t += gridDim.x) {
        const int j0 = t * 16;

        // A fragments: A[m][k] = atom_fea[j0+m][k]
        bf16x8 afrag[4];
#pragma unroll
        for (int c = 0; c < 4; ++c) {
            const float* base = &atom_fea[(size_t)(j0 + m) * ATOMF + c * 32 + quad * 8];
            const float4 f0 = *(const float4*)(base);
            const float4 f1 = *(const float4*)(base + 4);
            afrag[c] = to_bf16x8(f0, f1);
        }

        f32x4 acc[2] = { {0.f,0.f,0.f,0.f}, {0.f,0.f,0.f,0.f} };
#pragma unroll
        for (int c = 0; c < 4; ++c)
#pragma unroll
            for (int nb = 0; nb < 2; ++nb)
                acc[nb] = __builtin_amdgcn_mfma_f32_16x16x32_bf16(
                    afrag[c], bfrag[c][nb], acc[nb], 0, 0, 0);

        // scales for rows quad*4 + r: lane m loads (rep=p, word=which), 8-lane
        // butterfly sums over reps, xor-8 pairs s with c; all 16 lanes of the
        // quad end up with the final scale (no broadcast needed).
        float scv[4];
#pragma unroll
        for (int r = 0; r < 4; ++r) {
            const int j = j0 + quad * 4 + r;
            float v = (p < nrep) ? SC[(size_t)p * (2 * NATOM) + 2 * j + which] : 0.f;
#pragma unroll
            for (int off = 1; off < 8; off <<= 1)
                v += __shfl_xor(v, off, 64);
            const float o = __shfl_xor(v, 8, 64);
            const float s = which ? o : v;
            const float c = which ? v : o;
            // S_true = s + c*b2; out scale = S_true/max(c,1)/sqrt(128)
            scv[r] = (s + c * b2_0) / fmaxf(c, 1.0f) * 0.08838834764831843f;
        }

#pragma unroll
        for (int nb = 0; nb < 2; ++nb)
#pragma unroll
            for (int r = 0; r < 4; ++r)
                out[(size_t)(j0 + quad * 4 + r) * ATOMF + (wave * 2 + nb) * 16 + m] =
                    acc[nb][r] * scv[r];
    }
}

extern "C" void kernel_launch(void* const* d_in, const int* in_sizes, int n_in,
                              void* d_out, int out_size, void* d_ws, size_t ws_size,
                              hipStream_t stream) {
    const float* atom_fea = (const float*)d_in[0];
    const float* nbr_fea  = (const float*)d_in[1];
    const int*   nbr_idx  = (const int*)d_in[2];    // harness delivers integer inputs as int32
    const float* w1       = (const float*)d_in[3];
    const float* b1       = (const float*)d_in[4];
    const float* w2       = (const float*)d_in[5];
    const float* b2       = (const float*)d_in[6];
    const float* tp_w     = (const float*)d_in[7];
    float* out = (float*)d_out;

    float* SC = (float*)d_ws;       // nrep x [50000 x (scalar_sum, count) interleaved]

    int nrep = (ws_size >= (size_t)NREP_MAX * 2 * NATOM * sizeof(float)) ? NREP_MAX : 1;

    hipMemsetAsync(d_ws, 0, (size_t)nrep * 2 * NATOM * sizeof(float), stream);

    edge_kernel<<<2048, 256, 0, stream>>>(nbr_fea, nbr_idx, w1, b1, w2, SC, nrep - 1);
    atom_kernel<<<1024, 256, 0, stream>>>(atom_fea, tp_w, SC, b2, out, nrep);
}

// Round 3
// 583.424 us; speedup vs baseline: 1.0986x; 1.0663x over previous
//
#include <hip/hip_runtime.h>
#include <hip/hip_bf16.h>

#define NATOM 50000
#define MNBR  32
#define NEDGE (NATOM * MNBR)   // 1,600,000 (divisible by 16)
#define ATOMF 128
#define NBRF  64
#define SHDIM 9
#define NREP_MAX 8             // scatter-accumulator replicas (contention /8)
#define CNT_SCALE 4294967296.0 // 2^32: count lives in the high bits of the f64

typedef float  f32x4  __attribute__((ext_vector_type(4)));
typedef __bf16 bf16x8 __attribute__((ext_vector_type(8)));

// Native-op softplus: max(x,0) + ln2 * log2(1 + exp2(-|x|*log2e)).
// v_exp_f32/v_log_f32 are ~2-ULP; error invisible under bf16 matmul noise.
__device__ __forceinline__ float softplus_f(float x) {
    float e = __builtin_amdgcn_exp2f(-fabsf(x) * 1.44269504089f);
    float l = __builtin_amdgcn_logf(1.0f + e);   // log2
    return fmaxf(x, 0.0f) + 0.69314718056f * l;
}

__device__ __forceinline__ bf16x8 to_bf16x8(float4 lo, float4 hi) {
    bf16x8 r;
    r[0] = (__bf16)lo.x; r[1] = (__bf16)lo.y; r[2] = (__bf16)lo.z; r[3] = (__bf16)lo.w;
    r[4] = (__bf16)hi.x; r[5] = (__bf16)hi.y; r[6] = (__bf16)hi.z; r[7] = (__bf16)hi.w;
    return r;
}

// Edge kernel: per edge e, scalar_e = softplus(nbr_fea_e @ w1 + b1) . w2[:,0]
// (b2[0] deferred to the rescale: S_true = S + C*b2).
// One-deep software pipeline: next tile's 4 float4 A-loads + idx load issue
// before the current tile's MFMA/softplus/shfl tail (cross-tile MLP).
// Scatter: ONE f64 atomic per edge. Value encodes (scalar, count) as
// val + 2^32; decode in atom_kernel. f64 accumulation is MORE precise than
// the old per-edge f32 atomics, and halves atomic instruction count.
// SC has NREP replicas indexed by blockIdx&rep_mask (XCD-local under
// round-robin dispatch; same-address contention /8).
__global__ __launch_bounds__(256, 4) void edge_kernel(
    const float* __restrict__ nbr_fea, const int* __restrict__ nbr_idx,
    const float* __restrict__ w1, const float* __restrict__ b1,
    const float* __restrict__ w2,
    double* __restrict__ SC, int rep_mask)
{
    const int lane = threadIdx.x & 63;
    const int m    = lane & 15;    // A-row index (edge) / D-col index (feature)
    const int quad = lane >> 4;    // k-block / D-row-block index
    const int wave_id = (int)((blockIdx.x * blockDim.x + threadIdx.x) >> 6);
    const int nwaves  = (int)((gridDim.x * blockDim.x) >> 6);

    double* mySC = SC + (size_t)(blockIdx.x & (unsigned)rep_mask) * NATOM;

    // B fragments: B[k][n] = w1[k][n]; lane holds k = c*32 + quad*8 + j, n = nb*16 + m
    bf16x8 bfrag[2][4];
#pragma unroll
    for (int c = 0; c < 2; ++c)
#pragma unroll
        for (int nb = 0; nb < 4; ++nb)
#pragma unroll
            for (int j = 0; j < 8; ++j)
                bfrag[c][nb][j] = (__bf16)w1[(c * 32 + quad * 8 + j) * NBRF + nb * 16 + m];

    float b1v[4], w2v[4];
#pragma unroll
    for (int nb = 0; nb < 4; ++nb) {
        b1v[nb] = b1[nb * 16 + m];
        w2v[nb] = w2[(nb * 16 + m) * SHDIM + 0];  // w2 is (64,9) row-major; col 0
    }

    const int ntiles = NEDGE / 16;
    int t = wave_id;
    if (t >= ntiles) return;

    // prologue: prefetch tile t  (offsets within row: c*32 + quad*8 (+4))
    float4 pf0, pf1, pf2, pf3;
    int pjj;
    {
        const float* base = &nbr_fea[(size_t)(t * 16 + m) * NBRF + quad * 8];
        pf0 = *(const float4*)(base);
        pf1 = *(const float4*)(base + 4);
        pf2 = *(const float4*)(base + 32);
        pf3 = *(const float4*)(base + 36);
        pjj = nbr_idx[t * 16 + (lane & 15)];   // all lanes: avoids exec-mask dance
    }

    for (;;) {
        const int tn = t + nwaves;
        const bool more = (tn < ntiles);

        // consume prefetch into fragments before overwriting
        const bf16x8 af0 = to_bf16x8(pf0, pf1);
        const bf16x8 af1 = to_bf16x8(pf2, pf3);
        int jc = pjj;
        jc = (jc < 0) ? 0 : (jc >= NATOM ? NATOM - 1 : jc);  // never fault

        // issue next tile's loads now; waitcnt lands at next iteration's cvt
        if (more) {
            const float* base = &nbr_fea[(size_t)(tn * 16 + m) * NBRF + quad * 8];
            pf0 = *(const float4*)(base);
            pf1 = *(const float4*)(base + 4);
            pf2 = *(const float4*)(base + 32);
            pf3 = *(const float4*)(base + 36);
            pjj = nbr_idx[tn * 16 + (lane & 15)];
        }

        f32x4 acc[4] = { {0.f,0.f,0.f,0.f}, {0.f,0.f,0.f,0.f},
                         {0.f,0.f,0.f,0.f}, {0.f,0.f,0.f,0.f} };
#pragma unroll
        for (int nb = 0; nb < 4; ++nb) {
            acc[nb] = __builtin_amdgcn_mfma_f32_16x16x32_bf16(af0, bfrag[0][nb], acc[nb], 0, 0, 0);
            acc[nb] = __builtin_amdgcn_mfma_f32_16x16x32_bf16(af1, bfrag[1][nb], acc[nb], 0, 0, 0);
        }

        // D layout: col(feature) = nb*16 + m, row(edge-local) = quad*4 + reg
        float part[4] = {0.f, 0.f, 0.f, 0.f};
#pragma unroll
        for (int nb = 0; nb < 4; ++nb)
#pragma unroll
            for (int r = 0; r < 4; ++r)
                part[r] += softplus_f(acc[nb][r] + b1v[nb]) * w2v[nb];

        // butterfly over the 16 lanes of the quad-group (feature dimension);
        // afterwards every lane of quad-group q holds sums for edges e0+q*4+{0..3}
#pragma unroll
        for (int off = 1; off < 16; off <<= 1)
#pragma unroll
            for (int r = 0; r < 4; ++r)
                part[r] += __shfl_xor(part[r], off, 64);

        // scatter: lane (quad, m<4) owns edge e0 + quad*4 + m.
        // It already holds the value (part[m]); fetch the index with ONE shuffle
        // from lane quad*4+m (which loaded idx[e0 + quad*4 + m]).
        const int rr  = m & 3;
        const float val = (rr == 0) ? part[0] : (rr == 1) ? part[1]
                         : (rr == 2) ? part[2] : part[3];
        const int jje = __shfl(jc, (quad << 2) | rr, 64);

        if (m < 4)
            unsafeAtomicAdd(&mySC[jje], (double)val + CNT_SCALE);

        if (!more) break;
        t = tn;
    }
}

// Atom kernel: out[j][f] = (atom_fea[j] @ tp_w)[f] * (S[j]+C[j]*b2)/max(C[j],1)/sqrt(128)
// SC replicas summed in f64 with a parallel 8-lane butterfly, then decoded:
// count = rint(total/2^32), S = total - count*2^32.
__global__ __launch_bounds__(256) void atom_kernel(
    const float* __restrict__ atom_fea, const float* __restrict__ tp_w,
    const double* __restrict__ SC, const float* __restrict__ b2,
    float* __restrict__ out, int nrep)
{
    const int lane = threadIdx.x & 63;
    const int wave = threadIdx.x >> 6;   // feature half-block: nb_global = wave*2 + nb
    const int m    = lane & 15;
    const int quad = lane >> 4;
    const float b2_0 = b2[0];

    // B fragments: B[k][n] = tp_w[k][n]; k = c*32 + quad*8 + j, n = (wave*2+nb)*16 + m
    bf16x8 bfrag[4][2];
#pragma unroll
    for (int c = 0; c < 4; ++c)
#pragma unroll
        for (int nb = 0; nb < 2; ++nb)
#pragma unroll
            for (int j = 0; j < 8; ++j)
                bfrag[c][nb][j] =
                    (__bf16)tp_w[(c * 32 + quad * 8 + j) * ATOMF + (wave * 2 + nb) * 16 + m];

    const int p = m & 7;          // replica this lane reduces (lanes m<8 active)

    const int ntiles = NATOM / 16;  // 3125
    for (int t = blockIdx.x; t < ntiles; t += gridDim.x) {
        const int j0 = t * 16;

        // A fragments: A[m][k] = atom_fea[j0+m][k]
        bf16x8 afrag[4];
#pragma unroll
        for (int c = 0; c < 4; ++c) {
            const float* base = &atom_fea[(size_t)(j0 + m) * ATOMF + c * 32 + quad * 8];
            const float4 f0 = *(const float4*)(base);
            const float4 f1 = *(const float4*)(base + 4);
            afrag[c] = to_bf16x8(f0, f1);
        }

        f32x4 acc[2] = { {0.f,0.f,0.f,0.f}, {0.f,0.f,0.f,0.f} };
#pragma unroll
        for (int c = 0; c < 4; ++c)
#pragma unroll
            for (int nb = 0; nb < 2; ++nb)
                acc[nb] = __builtin_amdgcn_mfma_f32_16x16x32_bf16(
                    afrag[c], bfrag[c][nb], acc[nb], 0, 0, 0);

        // scales for rows quad*4 + r: lane m<8 loads replica p, 3-step f64
        // butterfly sums reps, xor-8 spreads to all 16 lanes of the quad.
        float scv[4];
#pragma unroll
        for (int r = 0; r < 4; ++r) {
            const int j = j0 + quad * 4 + r;
            double v = (m < 8 && p < nrep) ? SC[(size_t)p * NATOM + j] : 0.0;
#pragma unroll
            for (int off = 1; off < 8; off <<= 1)
                v += __shfl_xor(v, off, 64);
            v += __shfl_xor(v, 8, 64);
            // decode: count in high bits, scalar-sum in low
            const double cnt_d = __builtin_rint(v * (1.0 / CNT_SCALE));
            const float  cf    = (float)cnt_d;
            const float  sf    = (float)(v - cnt_d * CNT_SCALE);
            // S_true = sf + cf*b2; out scale = S_true/max(cf,1)/sqrt(128)
            scv[r] = (sf + cf * b2_0) / fmaxf(cf, 1.0f) * 0.08838834764831843f;
        }

#pragma unroll
        for (int nb = 0; nb < 2; ++nb)
#pragma unroll
            for (int r = 0; r < 4; ++r)
                out[(size_t)(j0 + quad * 4 + r) * ATOMF + (wave * 2 + nb) * 16 + m] =
                    acc[nb][r] * scv[r];
    }
}

extern "C" void kernel_launch(void* const* d_in, const int* in_sizes, int n_in,
                              void* d_out, int out_size, void* d_ws, size_t ws_size,
                              hipStream_t stream) {
    const float* atom_fea = (const float*)d_in[0];
    const float* nbr_fea  = (const float*)d_in[1];
    const int*   nbr_idx  = (const int*)d_in[2];    // harness delivers integer inputs as int32
    const float* w1       = (const float*)d_in[3];
    const float* b1       = (const float*)d_in[4];
    const float* w2       = (const float*)d_in[5];
    const float* b2       = (const float*)d_in[6];
    const float* tp_w     = (const float*)d_in[7];
    float* out = (float*)d_out;

    double* SC = (double*)d_ws;     // nrep x [NATOM f64: count*2^32 + scalar_sum]

    int nrep = (ws_size >= (size_t)NREP_MAX * NATOM * sizeof(double)) ? NREP_MAX : 1;

    hipMemsetAsync(d_ws, 0, (size_t)nrep * NATOM * sizeof(double), stream);

    edge_kernel<<<2048, 256, 0, stream>>>(nbr_fea, nbr_idx, w1, b1, w2, SC, nrep - 1);
    atom_kernel<<<1024, 256, 0, stream>>>(atom_fea, tp_w, SC, b2, out, nrep);
}